// Round 1
// baseline (350.364 us; speedup 1.0000x reference)
//
#include <hip/hip_runtime.h>

#define IN_CH   128
#define OUT_CH  64
#define GEMM_NODES 32   // nodes per block in the GEMM kernel

// ---------------------------------------------------------------------------
// Kernel 1: A = x @ (W_main_in + W_shared),  B = x @ (W_main_out + W_shared)
// Block = 256 threads (4 waves). Each block: 32 nodes. Each wave: 8 nodes,
// lane = output channel. Weights staged in LDS as float2 (in|out interleaved),
// x tile staged as float4. Each b64 weight read feeds 16 FMAs (8 nodes x 2).
// ---------------------------------------------------------------------------
__global__ __launch_bounds__(256, 2)
void gemm_kernel(const float* __restrict__ x,
                 const float* __restrict__ Wmi,
                 const float* __restrict__ Wmo,
                 const float* __restrict__ Wsh,
                 float* __restrict__ A,
                 float* __restrict__ B,
                 int n_nodes)
{
    __shared__ float2 WS[IN_CH][OUT_CH];          // 64 KB: (Win+Ws, Wout+Ws)
    __shared__ float4 XS[GEMM_NODES][IN_CH / 4];  // 16 KB

    const int tid = threadIdx.x;
    const long long node0 = (long long)blockIdx.x * GEMM_NODES;

    // Stage combined weights (coalesced float4 reads, 2048 float4 / 256 thr)
    {
        const float4* wmi4 = (const float4*)Wmi;
        const float4* wmo4 = (const float4*)Wmo;
        const float4* wsh4 = (const float4*)Wsh;
        for (int i = tid; i < (IN_CH * OUT_CH) / 4; i += 256) {
            float4 a = wmi4[i], o = wmo4[i], s = wsh4[i];
            int k = i >> 4;              // float index 4i / 64
            int c = (i & 15) << 2;
            WS[k][c + 0] = make_float2(a.x + s.x, o.x + s.x);
            WS[k][c + 1] = make_float2(a.y + s.y, o.y + s.y);
            WS[k][c + 2] = make_float2(a.z + s.z, o.z + s.z);
            WS[k][c + 3] = make_float2(a.w + s.w, o.w + s.w);
        }
    }

    // Stage x tile (1024 float4 / 256 thr)
    {
        const float4* x4 = (const float4*)(x + node0 * IN_CH);
        for (int i = tid; i < GEMM_NODES * IN_CH / 4; i += 256) {
            int n = i >> 5;       // / 32 float4 per row
            int kk = i & 31;
            if (node0 + n < n_nodes) XS[n][kk] = x4[i];
        }
    }
    __syncthreads();

    const int wave = tid >> 6;
    const int lane = tid & 63;     // output channel
    const int nbase = wave * 8;    // 8 nodes per wave

    float accA[8], accB[8];
#pragma unroll
    for (int j = 0; j < 8; ++j) { accA[j] = 0.f; accB[j] = 0.f; }

    for (int kk = 0; kk < IN_CH / 4; ++kk) {
        float2 w0 = WS[kk * 4 + 0][lane];
        float2 w1 = WS[kk * 4 + 1][lane];
        float2 w2 = WS[kk * 4 + 2][lane];
        float2 w3 = WS[kk * 4 + 3][lane];
#pragma unroll
        for (int j = 0; j < 8; ++j) {
            float4 xv = XS[nbase + j][kk];   // wave-uniform -> LDS broadcast
            accA[j] += xv.x * w0.x + xv.y * w1.x + xv.z * w2.x + xv.w * w3.x;
            accB[j] += xv.x * w0.y + xv.y * w1.y + xv.z * w2.y + xv.w * w3.y;
        }
    }

#pragma unroll
    for (int j = 0; j < 8; ++j) {
        long long n = node0 + nbase + j;
        if (n < n_nodes) {
            A[n * OUT_CH + lane] = accA[j];
            B[n * OUT_CH + lane] = accB[j];
        }
    }
}

// ---------------------------------------------------------------------------
// Kernel 2: CSR row pointers via lower_bound on the sorted target arrays.
// Thread i in [0, 2*(n_nodes+1)): first half -> in-set, second half -> out-set.
// ---------------------------------------------------------------------------
__global__ void rowptr_kernel(const int* __restrict__ tgtIn,
                              const int* __restrict__ tgtOut,
                              int* __restrict__ rpIn,
                              int* __restrict__ rpOut,
                              int n_nodes, int neIn, int neOut)
{
    int i = blockIdx.x * blockDim.x + threadIdx.x;
    int half = n_nodes + 1;
    if (i >= 2 * half) return;
    const int* tgt; int* rp; int t; int ne;
    if (i < half) { tgt = tgtIn;  rp = rpIn;  t = i;        ne = neIn; }
    else          { tgt = tgtOut; rp = rpOut; t = i - half; ne = neOut; }
    int lo = 0, hi = ne;
    while (lo < hi) {
        int mid = (lo + hi) >> 1;
        if (tgt[mid] < t) lo = mid + 1; else hi = mid;
    }
    rp[t] = lo;
}

// ---------------------------------------------------------------------------
// Kernel 3: segmented weighted gather-sum + epilogue.
// One wave per node; lane = channel. Edge (src,w) loaded coalesced in batches
// of 64, broadcast via __shfl; H-row gathers are coalesced 256 B loads.
// ---------------------------------------------------------------------------
__device__ __forceinline__
float segsum(const float* __restrict__ H, int e0, int e1,
             const int* __restrict__ src, const float* __restrict__ ew,
             int lane)
{
    float acc = 0.f;
    for (int base = e0; base < e1; base += 64) {
        int cnt = min(64, e1 - base);
        int s = 0; float w = 0.f;
        if (lane < cnt) { s = src[base + lane]; w = ew[base + lane]; }
        for (int j = 0; j < cnt; ++j) {
            int   sj = __shfl(s, j);
            float wj = __shfl(w, j);
            acc += wj * H[sj * OUT_CH + lane];
        }
    }
    return acc;
}

__global__ __launch_bounds__(256)
void prop_kernel(const float* __restrict__ A, const float* __restrict__ B,
                 const int* __restrict__ rpIn, const int* __restrict__ rpOut,
                 const int* __restrict__ srcIn, const float* __restrict__ ewIn,
                 const int* __restrict__ srcOut, const float* __restrict__ ewOut,
                 const float* __restrict__ bmi, const float* __restrict__ bmo,
                 const float* __restrict__ bsi, const float* __restrict__ bso,
                 const float* __restrict__ Cin, const float* __restrict__ Cout,
                 float* __restrict__ out, int n_nodes)
{
    const int lane = threadIdx.x & 63;
    const int wave = threadIdx.x >> 6;
    const int t = blockIdx.x * 4 + wave;
    if (t >= n_nodes) return;

    float ic = segsum(A, rpIn[t], rpIn[t + 1], srcIn, ewIn, lane);
    float oc = segsum(B, rpOut[t], rpOut[t + 1], srcOut, ewOut, lane);

    float bin  = bmi[lane] + bsi[lane];
    float bout = bmo[lane] + bso[lane];
    out[t * OUT_CH + lane] = Cin[t] * (ic + bin) + Cout[t] * (oc + bout);
}

// ---------------------------------------------------------------------------
extern "C" void kernel_launch(void* const* d_in, const int* in_sizes, int n_in,
                              void* d_out, int out_size, void* d_ws, size_t ws_size,
                              hipStream_t stream)
{
    const float* x    = (const float*)d_in[0];
    const float* Wmi  = (const float*)d_in[1];
    const float* Wmo  = (const float*)d_in[2];
    const float* Wsh  = (const float*)d_in[3];
    const float* bmi  = (const float*)d_in[4];
    const float* bmo  = (const float*)d_in[5];
    const float* bsi  = (const float*)d_in[6];
    const float* bso  = (const float*)d_in[7];
    const float* Cin  = (const float*)d_in[8];
    const float* Cout = (const float*)d_in[9];
    const int*   eiIn  = (const int*)d_in[10];
    const float* ewIn  = (const float*)d_in[11];
    const int*   eiOut = (const int*)d_in[12];
    const float* ewOut = (const float*)d_in[13];

    const int n_nodes = in_sizes[0] / IN_CH;   // 100000
    const int neIn  = in_sizes[11];            // 1000000
    const int neOut = in_sizes[13];

    const int* srcIn  = eiIn;                  // edge_index[0]
    const int* tgtIn  = eiIn + neIn;           // edge_index[1] (sorted)
    const int* srcOut = eiOut;
    const int* tgtOut = eiOut + neOut;

    // Workspace layout: A | B | rpIn | rpOut
    char* ws = (char*)d_ws;
    size_t NA = (size_t)n_nodes * OUT_CH * sizeof(float);
    float* A  = (float*)ws;
    float* Bm = (float*)(ws + NA);
    int* rpIn  = (int*)(ws + 2 * NA);
    int* rpOut = rpIn + (n_nodes + 1);

    // 1) dense transform (fused: both combined weight matrices)
    int gblocks = (n_nodes + GEMM_NODES - 1) / GEMM_NODES;
    gemm_kernel<<<gblocks, 256, 0, stream>>>(x, Wmi, Wmo, Wsh, A, Bm, n_nodes);

    // 2) row pointers for both edge sets
    int rp_threads = 2 * (n_nodes + 1);
    rowptr_kernel<<<(rp_threads + 255) / 256, 256, 0, stream>>>(
        tgtIn, tgtOut, rpIn, rpOut, n_nodes, neIn, neOut);

    // 3) segmented gather-sum + epilogue
    prop_kernel<<<(n_nodes + 3) / 4, 256, 0, stream>>>(
        A, Bm, rpIn, rpOut, srcIn, ewIn, srcOut, ewOut,
        bmi, bmo, bsi, bso, Cin, Cout, (float*)d_out, n_nodes);
}

// Round 2
// 298.905 us; speedup vs baseline: 1.1722x; 1.1722x over previous
//
#include <hip/hip_runtime.h>

#define IN_CH   128
#define OUT_CH  64
#define GEMM_NODES 32   // nodes per block in the GEMM kernel

// ---------------------------------------------------------------------------
// Kernel 1: A = x @ (W_main_in + W_shared),  B = x @ (W_main_out + W_shared)
// Block = 256 threads (4 waves). Each block: 32 nodes. Each wave: 8 nodes,
// lane = output channel. Weights staged in LDS as float2 (in|out interleaved),
// x tile staged as float4. Each b64 weight read feeds 16 FMAs (8 nodes x 2).
// ---------------------------------------------------------------------------
__global__ __launch_bounds__(256, 2)
void gemm_kernel(const float* __restrict__ x,
                 const float* __restrict__ Wmi,
                 const float* __restrict__ Wmo,
                 const float* __restrict__ Wsh,
                 float* __restrict__ A,
                 float* __restrict__ B,
                 int n_nodes)
{
    __shared__ float2 WS[IN_CH][OUT_CH];          // 64 KB: (Win+Ws, Wout+Ws)
    __shared__ float4 XS[GEMM_NODES][IN_CH / 4];  // 16 KB

    const int tid = threadIdx.x;
    const long long node0 = (long long)blockIdx.x * GEMM_NODES;

    // Stage combined weights (coalesced float4 reads, 2048 float4 / 256 thr)
    {
        const float4* wmi4 = (const float4*)Wmi;
        const float4* wmo4 = (const float4*)Wmo;
        const float4* wsh4 = (const float4*)Wsh;
        for (int i = tid; i < (IN_CH * OUT_CH) / 4; i += 256) {
            float4 a = wmi4[i], o = wmo4[i], s = wsh4[i];
            int k = i >> 4;              // float index 4i / 64
            int c = (i & 15) << 2;
            WS[k][c + 0] = make_float2(a.x + s.x, o.x + s.x);
            WS[k][c + 1] = make_float2(a.y + s.y, o.y + s.y);
            WS[k][c + 2] = make_float2(a.z + s.z, o.z + s.z);
            WS[k][c + 3] = make_float2(a.w + s.w, o.w + s.w);
        }
    }

    // Stage x tile (1024 float4 / 256 thr)
    {
        const float4* x4 = (const float4*)(x + node0 * IN_CH);
        for (int i = tid; i < GEMM_NODES * IN_CH / 4; i += 256) {
            int n = i >> 5;       // / 32 float4 per row
            int kk = i & 31;
            if (node0 + n < n_nodes) XS[n][kk] = x4[i];
        }
    }
    __syncthreads();

    const int wave = tid >> 6;
    const int lane = tid & 63;     // output channel
    const int nbase = wave * 8;    // 8 nodes per wave

    float accA[8], accB[8];
#pragma unroll
    for (int j = 0; j < 8; ++j) { accA[j] = 0.f; accB[j] = 0.f; }

    for (int kk = 0; kk < IN_CH / 4; ++kk) {
        float2 w0 = WS[kk * 4 + 0][lane];
        float2 w1 = WS[kk * 4 + 1][lane];
        float2 w2 = WS[kk * 4 + 2][lane];
        float2 w3 = WS[kk * 4 + 3][lane];
#pragma unroll
        for (int j = 0; j < 8; ++j) {
            float4 xv = XS[nbase + j][kk];   // wave-uniform -> LDS broadcast
            accA[j] += xv.x * w0.x + xv.y * w1.x + xv.z * w2.x + xv.w * w3.x;
            accB[j] += xv.x * w0.y + xv.y * w1.y + xv.z * w2.y + xv.w * w3.y;
        }
    }

#pragma unroll
    for (int j = 0; j < 8; ++j) {
        long long n = node0 + nbase + j;
        if (n < n_nodes) {
            A[n * OUT_CH + lane] = accA[j];
            B[n * OUT_CH + lane] = accB[j];
        }
    }
}

// ---------------------------------------------------------------------------
// Kernel 2: CSR row pointers via lower_bound on the sorted target arrays.
// ---------------------------------------------------------------------------
__global__ void rowptr_kernel(const int* __restrict__ tgtIn,
                              const int* __restrict__ tgtOut,
                              int* __restrict__ rpIn,
                              int* __restrict__ rpOut,
                              int n_nodes, int neIn, int neOut)
{
    int i = blockIdx.x * blockDim.x + threadIdx.x;
    int half = n_nodes + 1;
    if (i >= 2 * half) return;
    const int* tgt; int* rp; int t; int ne;
    if (i < half) { tgt = tgtIn;  rp = rpIn;  t = i;        ne = neIn; }
    else          { tgt = tgtOut; rp = rpOut; t = i - half; ne = neOut; }
    int lo = 0, hi = ne;
    while (lo < hi) {
        int mid = (lo + hi) >> 1;
        if (tgt[mid] < t) lo = mid + 1; else hi = mid;
    }
    rp[t] = lo;
}

// ---------------------------------------------------------------------------
// Kernel 3: segmented weighted gather-sum + epilogue.
// One wave per node; lane = channel. Unroll x4 with 4 accumulators so 4
// gathers are in flight per wave before the first waitcnt (MLP fix for the
// R1 latency bound: 23% VALUBusy / 25% HBM at 140 us).
// ---------------------------------------------------------------------------
__device__ __forceinline__
float segsum(const float* __restrict__ H, int e0, int e1,
             const int* __restrict__ src, const float* __restrict__ ew,
             int lane)
{
    float acc0 = 0.f, acc1 = 0.f, acc2 = 0.f, acc3 = 0.f;
    for (int base = e0; base < e1; base += 64) {
        int cnt = min(64, e1 - base);
        int s = 0; float w = 0.f;
        if (lane < cnt) { s = src[base + lane]; w = ew[base + lane]; }
        int j = 0;
        for (; j + 4 <= cnt; j += 4) {
            int   s0 = __shfl(s, j + 0), s1 = __shfl(s, j + 1);
            int   s2 = __shfl(s, j + 2), s3 = __shfl(s, j + 3);
            float w0 = __shfl(w, j + 0), w1 = __shfl(w, j + 1);
            float w2 = __shfl(w, j + 2), w3 = __shfl(w, j + 3);
            float v0 = H[(long long)s0 * OUT_CH + lane];
            float v1 = H[(long long)s1 * OUT_CH + lane];
            float v2 = H[(long long)s2 * OUT_CH + lane];
            float v3 = H[(long long)s3 * OUT_CH + lane];
            acc0 += w0 * v0;
            acc1 += w1 * v1;
            acc2 += w2 * v2;
            acc3 += w3 * v3;
        }
        for (; j < cnt; ++j) {
            int   sj = __shfl(s, j);
            float wj = __shfl(w, j);
            acc0 += wj * H[(long long)sj * OUT_CH + lane];
        }
    }
    return (acc0 + acc1) + (acc2 + acc3);
}

__global__ __launch_bounds__(256)
void prop_kernel(const float* __restrict__ A, const float* __restrict__ B,
                 const int* __restrict__ rpIn, const int* __restrict__ rpOut,
                 const int* __restrict__ srcIn, const float* __restrict__ ewIn,
                 const int* __restrict__ srcOut, const float* __restrict__ ewOut,
                 const float* __restrict__ bmi, const float* __restrict__ bmo,
                 const float* __restrict__ bsi, const float* __restrict__ bso,
                 const float* __restrict__ Cin, const float* __restrict__ Cout,
                 float* __restrict__ out, int n_nodes)
{
    const int lane = threadIdx.x & 63;
    const int wave = threadIdx.x >> 6;
    const int t = blockIdx.x * 4 + wave;
    if (t >= n_nodes) return;

    // Hoist epilogue operands so they're in flight during the gathers.
    float bin  = bmi[lane] + bsi[lane];
    float bout = bmo[lane] + bso[lane];
    float ci = Cin[t], co = Cout[t];

    float ic = segsum(A, rpIn[t], rpIn[t + 1], srcIn, ewIn, lane);
    float oc = segsum(B, rpOut[t], rpOut[t + 1], srcOut, ewOut, lane);

    out[t * OUT_CH + lane] = ci * (ic + bin) + co * (oc + bout);
}

// ---------------------------------------------------------------------------
extern "C" void kernel_launch(void* const* d_in, const int* in_sizes, int n_in,
                              void* d_out, int out_size, void* d_ws, size_t ws_size,
                              hipStream_t stream)
{
    const float* x    = (const float*)d_in[0];
    const float* Wmi  = (const float*)d_in[1];
    const float* Wmo  = (const float*)d_in[2];
    const float* Wsh  = (const float*)d_in[3];
    const float* bmi  = (const float*)d_in[4];
    const float* bmo  = (const float*)d_in[5];
    const float* bsi  = (const float*)d_in[6];
    const float* bso  = (const float*)d_in[7];
    const float* Cin  = (const float*)d_in[8];
    const float* Cout = (const float*)d_in[9];
    const int*   eiIn  = (const int*)d_in[10];
    const float* ewIn  = (const float*)d_in[11];
    const int*   eiOut = (const int*)d_in[12];
    const float* ewOut = (const float*)d_in[13];

    const int n_nodes = in_sizes[0] / IN_CH;   // 100000
    const int neIn  = in_sizes[11];            // 1000000
    const int neOut = in_sizes[13];

    const int* srcIn  = eiIn;                  // edge_index[0]
    const int* tgtIn  = eiIn + neIn;           // edge_index[1] (sorted)
    const int* srcOut = eiOut;
    const int* tgtOut = eiOut + neOut;

    // Workspace layout: A | B | rpIn | rpOut
    char* ws = (char*)d_ws;
    size_t NA = (size_t)n_nodes * OUT_CH * sizeof(float);
    float* A  = (float*)ws;
    float* Bm = (float*)(ws + NA);
    int* rpIn  = (int*)(ws + 2 * NA);
    int* rpOut = rpIn + (n_nodes + 1);

    // 1) dense transform (fused: both combined weight matrices)
    int gblocks = (n_nodes + GEMM_NODES - 1) / GEMM_NODES;
    gemm_kernel<<<gblocks, 256, 0, stream>>>(x, Wmi, Wmo, Wsh, A, Bm, n_nodes);

    // 2) row pointers for both edge sets
    int rp_threads = 2 * (n_nodes + 1);
    rowptr_kernel<<<(rp_threads + 255) / 256, 256, 0, stream>>>(
        tgtIn, tgtOut, rpIn, rpOut, n_nodes, neIn, neOut);

    // 3) segmented gather-sum + epilogue
    prop_kernel<<<(n_nodes + 3) / 4, 256, 0, stream>>>(
        A, Bm, rpIn, rpOut, srcIn, ewIn, srcOut, ewOut,
        bmi, bmo, bsi, bso, Cin, Cout, (float*)d_out, n_nodes);
}

// Round 3
// 225.121 us; speedup vs baseline: 1.5563x; 1.3278x over previous
//
#include <hip/hip_runtime.h>

#define IN_CH   128
#define OUT_CH  64
#define M_TILE  64          // nodes per block in the MFMA GEMM
#define LDS_PITCH 136       // 128 bf16 + 8 pad -> 272 B row, kills bank conflicts

typedef __attribute__((ext_vector_type(8))) short short8;
typedef __attribute__((ext_vector_type(4))) float floatx4;

__device__ __forceinline__ unsigned short f2bf(float f) {
    union { float f; unsigned u; } v; v.f = f;
    unsigned r = v.u + 0x7fffu + ((v.u >> 16) & 1u);   // RNE
    return (unsigned short)(r >> 16);
}
__device__ __forceinline__ float bf2f(unsigned v) {
    union { unsigned u; float f; } c; c.u = v << 16;
    return c.f;
}

// ---------------------------------------------------------------------------
// Kernel 1 (MFMA): H = x_bf16 @ WcT^T where Wc = [Wmi+Ws | Wmo+Ws] (128x128).
// Block 256 thr = 4 waves, tile M=64 x N=128, K=128 fully LDS-resident.
// Wave w covers cols [w*32, w*32+32): waves 0,1 -> A (cols 0..63),
// waves 2,3 -> B (cols 64..127). 8 accum frags/wave, 32 MFMAs/wave.
// ---------------------------------------------------------------------------
__global__ __launch_bounds__(256, 3)
void gemm_kernel(const float* __restrict__ x,
                 const float* __restrict__ Wmi,
                 const float* __restrict__ Wmo,
                 const float* __restrict__ Wsh,
                 unsigned short* __restrict__ Abf,
                 unsigned short* __restrict__ Bbf,
                 int n_nodes)
{
    __shared__ unsigned short Wt[2 * OUT_CH][LDS_PITCH];  // WcT[n][k], 34.8 KB
    __shared__ unsigned short Xs[M_TILE][LDS_PITCH];      // X tile bf16, 17.4 KB

    const int tid = threadIdx.x;
    const long long node0 = (long long)blockIdx.x * M_TILE;

    // Stage combined weights, transposed (coalesced global reads).
    for (int i = tid; i < IN_CH * OUT_CH; i += 256) {
        int k = i >> 6, c = i & 63;
        float s = Wsh[i];
        Wt[c][k]          = f2bf(Wmi[i] + s);
        Wt[c + OUT_CH][k] = f2bf(Wmo[i] + s);
    }

    // Stage x tile as bf16 (float4 reads, uint2 LDS writes).
    {
        const float4* x4 = (const float4*)x;
        for (int i = tid; i < M_TILE * (IN_CH / 4); i += 256) {
            int row = i >> 5, c4 = i & 31;
            long long node = node0 + row;
            float4 v = make_float4(0.f, 0.f, 0.f, 0.f);
            if (node < n_nodes) v = x4[node * (IN_CH / 4) + c4];
            uint2 p;
            p.x = ((unsigned)f2bf(v.y) << 16) | f2bf(v.x);
            p.y = ((unsigned)f2bf(v.w) << 16) | f2bf(v.z);
            *(uint2*)&Xs[row][c4 * 4] = p;
        }
    }
    __syncthreads();

    const int w    = tid >> 6;
    const int lane = tid & 63;
    const int l15  = lane & 15;
    const int quad = lane >> 4;

    floatx4 acc[4][2];
#pragma unroll
    for (int mi = 0; mi < 4; ++mi)
#pragma unroll
        for (int ni = 0; ni < 2; ++ni)
            acc[mi][ni] = (floatx4){0.f, 0.f, 0.f, 0.f};

#pragma unroll
    for (int ks = 0; ks < 4; ++ks) {
        const int k0 = ks * 32 + quad * 8;
        short8 a0 = *(const short8*)&Xs[ 0 + l15][k0];
        short8 a1 = *(const short8*)&Xs[16 + l15][k0];
        short8 a2 = *(const short8*)&Xs[32 + l15][k0];
        short8 a3 = *(const short8*)&Xs[48 + l15][k0];
        short8 b0 = *(const short8*)&Wt[w * 32 +  0 + l15][k0];
        short8 b1 = *(const short8*)&Wt[w * 32 + 16 + l15][k0];
        acc[0][0] = __builtin_amdgcn_mfma_f32_16x16x32_bf16(a0, b0, acc[0][0], 0, 0, 0);
        acc[1][0] = __builtin_amdgcn_mfma_f32_16x16x32_bf16(a1, b0, acc[1][0], 0, 0, 0);
        acc[2][0] = __builtin_amdgcn_mfma_f32_16x16x32_bf16(a2, b0, acc[2][0], 0, 0, 0);
        acc[3][0] = __builtin_amdgcn_mfma_f32_16x16x32_bf16(a3, b0, acc[3][0], 0, 0, 0);
        acc[0][1] = __builtin_amdgcn_mfma_f32_16x16x32_bf16(a0, b1, acc[0][1], 0, 0, 0);
        acc[1][1] = __builtin_amdgcn_mfma_f32_16x16x32_bf16(a1, b1, acc[1][1], 0, 0, 0);
        acc[2][1] = __builtin_amdgcn_mfma_f32_16x16x32_bf16(a2, b1, acc[2][1], 0, 0, 0);
        acc[3][1] = __builtin_amdgcn_mfma_f32_16x16x32_bf16(a3, b1, acc[3][1], 0, 0, 0);
    }

    // Epilogue: C/D layout col = lane&15, row = quad*4 + r.
    unsigned short* Hout = (w < 2) ? Abf : Bbf;
    const int colb = (w & 1) * 32;
#pragma unroll
    for (int mi = 0; mi < 4; ++mi)
#pragma unroll
        for (int ni = 0; ni < 2; ++ni)
#pragma unroll
            for (int r = 0; r < 4; ++r) {
                long long row = node0 + mi * 16 + quad * 4 + r;
                if (row < n_nodes)
                    Hout[row * OUT_CH + colb + ni * 16 + l15] = f2bf(acc[mi][ni][r]);
            }
}

// ---------------------------------------------------------------------------
// Kernel 2: CSR row pointers via lower_bound on the sorted target arrays.
// ---------------------------------------------------------------------------
__global__ void rowptr_kernel(const int* __restrict__ tgtIn,
                              const int* __restrict__ tgtOut,
                              int* __restrict__ rpIn,
                              int* __restrict__ rpOut,
                              int n_nodes, int neIn, int neOut)
{
    int i = blockIdx.x * blockDim.x + threadIdx.x;
    int half = n_nodes + 1;
    if (i >= 2 * half) return;
    const int* tgt; int* rp; int t; int ne;
    if (i < half) { tgt = tgtIn;  rp = rpIn;  t = i;        ne = neIn; }
    else          { tgt = tgtOut; rp = rpOut; t = i - half; ne = neOut; }
    int lo = 0, hi = ne;
    while (lo < hi) {
        int mid = (lo + hi) >> 1;
        if (tgt[mid] < t) lo = mid + 1; else hi = mid;
    }
    rp[t] = lo;
}

// ---------------------------------------------------------------------------
// Kernel 3: segmented weighted gather-sum (bf16 H) + epilogue.
// One wave per node; lane = channel. 8 predicated slots per batch keep 8
// gathers in flight even for short segments (predicates are wave-uniform).
// ---------------------------------------------------------------------------
__device__ __forceinline__
float segsum(const unsigned short* __restrict__ H, int e0, int e1,
             const int* __restrict__ src, const float* __restrict__ ew,
             int lane)
{
    float a0 = 0.f, a1 = 0.f, a2 = 0.f, a3 = 0.f;
    for (int base = e0; base < e1; base += 64) {
        int cnt = min(64, e1 - base);
        int s = 0; float w = 0.f;
        if (lane < cnt) { s = src[base + lane]; w = ew[base + lane]; }
        for (int j = 0; j < cnt; j += 8) {
            int   sj[8]; float wj[8];
#pragma unroll
            for (int i = 0; i < 8; ++i) {
                int idx = j + i;               // wave-uniform
                int sel = (idx < cnt) ? idx : 0;
                sj[i] = __shfl(s, sel);
                float t = __shfl(w, sel);
                wj[i] = (idx < cnt) ? t : 0.f;
            }
            float v[8];
#pragma unroll
            for (int i = 0; i < 8; ++i)
                v[i] = bf2f(H[(long long)sj[i] * OUT_CH + lane]);
            a0 += wj[0] * v[0]; a1 += wj[1] * v[1];
            a2 += wj[2] * v[2]; a3 += wj[3] * v[3];
            a0 += wj[4] * v[4]; a1 += wj[5] * v[5];
            a2 += wj[6] * v[6]; a3 += wj[7] * v[7];
        }
    }
    return (a0 + a1) + (a2 + a3);
}

__global__ __launch_bounds__(256)
void prop_kernel(const unsigned short* __restrict__ A,
                 const unsigned short* __restrict__ B,
                 const int* __restrict__ rpIn, const int* __restrict__ rpOut,
                 const int* __restrict__ srcIn, const float* __restrict__ ewIn,
                 const int* __restrict__ srcOut, const float* __restrict__ ewOut,
                 const float* __restrict__ bmi, const float* __restrict__ bmo,
                 const float* __restrict__ bsi, const float* __restrict__ bso,
                 const float* __restrict__ Cin, const float* __restrict__ Cout,
                 float* __restrict__ out, int n_nodes)
{
    const int lane = threadIdx.x & 63;
    const int wave = threadIdx.x >> 6;
    const int t = blockIdx.x * 4 + wave;
    if (t >= n_nodes) return;

    float bin  = bmi[lane] + bsi[lane];
    float bout = bmo[lane] + bso[lane];
    float ci = Cin[t], co = Cout[t];

    float ic = segsum(A, rpIn[t], rpIn[t + 1], srcIn, ewIn, lane);
    float oc = segsum(B, rpOut[t], rpOut[t + 1], srcOut, ewOut, lane);

    out[t * OUT_CH + lane] = ci * (ic + bin) + co * (oc + bout);
}

// ---------------------------------------------------------------------------
extern "C" void kernel_launch(void* const* d_in, const int* in_sizes, int n_in,
                              void* d_out, int out_size, void* d_ws, size_t ws_size,
                              hipStream_t stream)
{
    const float* x    = (const float*)d_in[0];
    const float* Wmi  = (const float*)d_in[1];
    const float* Wmo  = (const float*)d_in[2];
    const float* Wsh  = (const float*)d_in[3];
    const float* bmi  = (const float*)d_in[4];
    const float* bmo  = (const float*)d_in[5];
    const float* bsi  = (const float*)d_in[6];
    const float* bso  = (const float*)d_in[7];
    const float* Cin  = (const float*)d_in[8];
    const float* Cout = (const float*)d_in[9];
    const int*   eiIn  = (const int*)d_in[10];
    const float* ewIn  = (const float*)d_in[11];
    const int*   eiOut = (const int*)d_in[12];
    const float* ewOut = (const float*)d_in[13];

    const int n_nodes = in_sizes[0] / IN_CH;   // 100000
    const int neIn  = in_sizes[11];            // 1000000
    const int neOut = in_sizes[13];

    const int* srcIn  = eiIn;                  // edge_index[0]
    const int* tgtIn  = eiIn + neIn;           // edge_index[1] (sorted)
    const int* srcOut = eiOut;
    const int* tgtOut = eiOut + neOut;

    // Workspace layout: Abf (bf16) | Bbf (bf16) | rpIn | rpOut
    char* ws = (char*)d_ws;
    size_t NH = (size_t)n_nodes * OUT_CH * sizeof(unsigned short);
    unsigned short* Abf = (unsigned short*)ws;
    unsigned short* Bbf = (unsigned short*)(ws + NH);
    int* rpIn  = (int*)(ws + 2 * NH);
    int* rpOut = rpIn + (n_nodes + 1);

    // 1) fused dense transform via MFMA (N=128 GEMM: [A|B] columns)
    int gblocks = (n_nodes + M_TILE - 1) / M_TILE;
    gemm_kernel<<<gblocks, 256, 0, stream>>>(x, Wmi, Wmo, Wsh, Abf, Bbf, n_nodes);

    // 2) row pointers for both edge sets
    int rp_threads = 2 * (n_nodes + 1);
    rowptr_kernel<<<(rp_threads + 255) / 256, 256, 0, stream>>>(
        tgtIn, tgtOut, rpIn, rpOut, n_nodes, neIn, neOut);

    // 3) segmented gather-sum + epilogue
    prop_kernel<<<(n_nodes + 3) / 4, 256, 0, stream>>>(
        Abf, Bbf, rpIn, rpOut, srcIn, ewIn, srcOut, ewOut,
        bmi, bmo, bsi, bso, Cin, Cout, (float*)d_out, n_nodes);
}

// Round 4
// 211.012 us; speedup vs baseline: 1.6604x; 1.0669x over previous
//
#include <hip/hip_runtime.h>

#define IN_CH   128
#define OUT_CH  64
#define M_TILE  128         // nodes per block in the MFMA GEMM
#define XS_PITCH 136        // 128 bf16 + 8 pad (272 B row) -> conflict-free frags

typedef __attribute__((ext_vector_type(8))) short short8;
typedef __attribute__((ext_vector_type(4))) float floatx4;

__device__ __forceinline__ unsigned short f2bf(float f) {
    union { float f; unsigned u; } v; v.f = f;
    unsigned r = v.u + 0x7fffu + ((v.u >> 16) & 1u);   // RNE
    return (unsigned short)(r >> 16);
}
__device__ __forceinline__ float bf2f(unsigned v) {
    union { unsigned u; float f; } c; c.u = v << 16;
    return c.f;
}

// ---------------------------------------------------------------------------
// Kernel 1 (prep): CSR row pointers (lower_bound over sorted targets) for both
// edge sets, PLUS bf16 pre-pack of the combined transposed weights
// WcT[n][k] = bf16(Wc[k][n]), Wc = [Wmi+Ws | Wmo+Ws]  (128x128).
// ---------------------------------------------------------------------------
__global__ void prep_kernel(const int* __restrict__ tgtIn,
                            const int* __restrict__ tgtOut,
                            const float* __restrict__ Wmi,
                            const float* __restrict__ Wmo,
                            const float* __restrict__ Wsh,
                            int* __restrict__ rpIn,
                            int* __restrict__ rpOut,
                            unsigned short* __restrict__ WcT,
                            int n_nodes, int neIn, int neOut)
{
    int i = blockIdx.x * blockDim.x + threadIdx.x;
    int half = n_nodes + 1;
    if (i < 2 * half) {
        const int* tgt; int* rp; int t; int ne;
        if (i < half) { tgt = tgtIn;  rp = rpIn;  t = i;        ne = neIn; }
        else          { tgt = tgtOut; rp = rpOut; t = i - half; ne = neOut; }
        int lo = 0, hi = ne;
        while (lo < hi) {
            int mid = (lo + hi) >> 1;
            if (tgt[mid] < t) lo = mid + 1; else hi = mid;
        }
        rp[t] = lo;
    } else {
        int j = i - 2 * half;
        if (j < 2 * OUT_CH * IN_CH) {
            int n = j >> 7, k = j & 127;     // n: output col of Wc, k: input ch
            float m = (n < OUT_CH) ? Wmi[k * OUT_CH + n]
                                   : Wmo[k * OUT_CH + (n - OUT_CH)];
            float s = Wsh[k * OUT_CH + (n & (OUT_CH - 1))];
            WcT[n * IN_CH + k] = f2bf(m + s);
        }
    }
}

// ---------------------------------------------------------------------------
// Kernel 2 (MFMA GEMM): H = x_bf16 @ WcT^T. Block = 256 thr (4 waves),
// tile M=128 x N=128, K=128. Wave w -> cols [w*32, w*32+32): waves 0,1 -> A,
// waves 2,3 -> B. B-fragments loaded straight from global WcT (32 KB, L2-hot);
// only the x tile goes through LDS (35 KB -> 3+ blocks/CU).
// ---------------------------------------------------------------------------
__global__ __launch_bounds__(256, 3)
void gemm_kernel(const float* __restrict__ x,
                 const unsigned short* __restrict__ WcT,
                 unsigned short* __restrict__ Abf,
                 unsigned short* __restrict__ Bbf,
                 int n_nodes)
{
    __shared__ unsigned short Xs[M_TILE][XS_PITCH];   // 34.8 KB

    const int tid  = threadIdx.x;
    const int w    = tid >> 6;
    const int lane = tid & 63;
    const int l15  = lane & 15;
    const int quad = lane >> 4;
    const long long node0 = (long long)blockIdx.x * M_TILE;

    // B-fragments: lane l15 holds WcT[n = w*32 + ni*16 + l15][k0 .. k0+8)
    short8 bfrag[4][2];
#pragma unroll
    for (int ks = 0; ks < 4; ++ks)
#pragma unroll
        for (int ni = 0; ni < 2; ++ni)
            bfrag[ks][ni] = *(const short8*)&WcT[(w * 32 + ni * 16 + l15) * IN_CH
                                                 + ks * 32 + quad * 8];

    // Stage x tile as bf16 (float4 reads, uint2 LDS writes). 16 iters/thread.
    {
        const float4* x4 = (const float4*)x;
        for (int i = tid; i < M_TILE * (IN_CH / 4); i += 256) {
            int row = i >> 5, c4 = i & 31;
            long long node = node0 + row;
            float4 v = make_float4(0.f, 0.f, 0.f, 0.f);
            if (node < n_nodes) v = x4[node * (IN_CH / 4) + c4];
            uint2 p;
            p.x = ((unsigned)f2bf(v.y) << 16) | f2bf(v.x);
            p.y = ((unsigned)f2bf(v.w) << 16) | f2bf(v.z);
            *(uint2*)&Xs[row][c4 * 4] = p;
        }
    }
    __syncthreads();

    floatx4 acc[8][2];
#pragma unroll
    for (int mi = 0; mi < 8; ++mi)
#pragma unroll
        for (int ni = 0; ni < 2; ++ni)
            acc[mi][ni] = (floatx4){0.f, 0.f, 0.f, 0.f};

#pragma unroll
    for (int ks = 0; ks < 4; ++ks) {
        const int k0 = ks * 32 + quad * 8;
#pragma unroll
        for (int mi = 0; mi < 8; ++mi) {
            short8 a = *(const short8*)&Xs[mi * 16 + l15][k0];
            acc[mi][0] = __builtin_amdgcn_mfma_f32_16x16x32_bf16(a, bfrag[ks][0], acc[mi][0], 0, 0, 0);
            acc[mi][1] = __builtin_amdgcn_mfma_f32_16x16x32_bf16(a, bfrag[ks][1], acc[mi][1], 0, 0, 0);
        }
    }

    // Epilogue: C/D layout col = lane&15, row = quad*4 + r.
    unsigned short* Hout = (w < 2) ? Abf : Bbf;
    const int colb = (w & 1) * 32;
#pragma unroll
    for (int mi = 0; mi < 8; ++mi)
#pragma unroll
        for (int ni = 0; ni < 2; ++ni)
#pragma unroll
            for (int r = 0; r < 4; ++r) {
                long long row = node0 + mi * 16 + quad * 4 + r;
                if (row < n_nodes)
                    Hout[row * OUT_CH + colb + ni * 16 + l15] = f2bf(acc[mi][ni][r]);
            }
}

// ---------------------------------------------------------------------------
// Kernel 3: segmented weighted gather-sum (bf16 H) + epilogue.
// One wave per node; lane = channel. Edge (src,w) batch-loaded coalesced,
// then broadcast via v_readlane -> SGPR, so the gather address is pure SALU
// (saddr-form global_load_ushort) and pad predication is s_cselect.
// Per edge: ~4 VALU (2 readlane + shift + fmac) + 1 VMEM.
// ---------------------------------------------------------------------------
__device__ __forceinline__
float segsum(const unsigned short* __restrict__ Hl, int e0, int e1,
             const int* __restrict__ src, const float* __restrict__ ew,
             int lane)
{
    float a0 = 0.f, a1 = 0.f, a2 = 0.f, a3 = 0.f;
    for (int base = e0; base < e1; base += 64) {
        int cnt = min(64, e1 - base);
        int s = 0; float w = 0.f;
        if (lane < cnt) { s = src[base + lane]; w = ew[base + lane]; }
        for (int j = 0; j < cnt; j += 8) {
            int sj[8]; float wj[8];
#pragma unroll
            for (int i = 0; i < 8; ++i) {
                int idx = j + i;                    // wave-uniform
                int sel = (idx < cnt) ? idx : 0;    // s_cselect
                sj[i] = __builtin_amdgcn_readlane(s, sel);
                int wi = __builtin_amdgcn_readlane(__float_as_int(w), sel);
                wj[i] = (idx < cnt) ? __int_as_float(wi) : 0.f;
            }
            float v[8];
#pragma unroll
            for (int i = 0; i < 8; ++i)
                v[i] = bf2f(Hl[(long long)sj[i] * OUT_CH]);
            a0 += wj[0] * v[0]; a1 += wj[1] * v[1];
            a2 += wj[2] * v[2]; a3 += wj[3] * v[3];
            a0 += wj[4] * v[4]; a1 += wj[5] * v[5];
            a2 += wj[6] * v[6]; a3 += wj[7] * v[7];
        }
    }
    return (a0 + a1) + (a2 + a3);
}

__global__ __launch_bounds__(256)
void prop_kernel(const unsigned short* __restrict__ A,
                 const unsigned short* __restrict__ B,
                 const int* __restrict__ rpIn, const int* __restrict__ rpOut,
                 const int* __restrict__ srcIn, const float* __restrict__ ewIn,
                 const int* __restrict__ srcOut, const float* __restrict__ ewOut,
                 const float* __restrict__ bmi, const float* __restrict__ bmo,
                 const float* __restrict__ bsi, const float* __restrict__ bso,
                 const float* __restrict__ Cin, const float* __restrict__ Cout,
                 float* __restrict__ out, int n_nodes)
{
    const int lane = threadIdx.x & 63;
    const int wv = __builtin_amdgcn_readfirstlane(threadIdx.x >> 6);
    const int t = blockIdx.x * 4 + wv;
    if (t >= n_nodes) return;

    float bin  = bmi[lane] + bsi[lane];
    float bout = bmo[lane] + bso[lane];
    float ci = Cin[t], co = Cout[t];

    int ei0 = __builtin_amdgcn_readfirstlane(rpIn[t]);
    int ei1 = __builtin_amdgcn_readfirstlane(rpIn[t + 1]);
    int eo0 = __builtin_amdgcn_readfirstlane(rpOut[t]);
    int eo1 = __builtin_amdgcn_readfirstlane(rpOut[t + 1]);

    float ic = segsum(A + lane, ei0, ei1, srcIn, ewIn, lane);
    float oc = segsum(B + lane, eo0, eo1, srcOut, ewOut, lane);

    out[t * OUT_CH + lane] = ci * (ic + bin) + co * (oc + bout);
}

// ---------------------------------------------------------------------------
extern "C" void kernel_launch(void* const* d_in, const int* in_sizes, int n_in,
                              void* d_out, int out_size, void* d_ws, size_t ws_size,
                              hipStream_t stream)
{
    const float* x    = (const float*)d_in[0];
    const float* Wmi  = (const float*)d_in[1];
    const float* Wmo  = (const float*)d_in[2];
    const float* Wsh  = (const float*)d_in[3];
    const float* bmi  = (const float*)d_in[4];
    const float* bmo  = (const float*)d_in[5];
    const float* bsi  = (const float*)d_in[6];
    const float* bso  = (const float*)d_in[7];
    const float* Cin  = (const float*)d_in[8];
    const float* Cout = (const float*)d_in[9];
    const int*   eiIn  = (const int*)d_in[10];
    const float* ewIn  = (const float*)d_in[11];
    const int*   eiOut = (const int*)d_in[12];
    const float* ewOut = (const float*)d_in[13];

    const int n_nodes = in_sizes[0] / IN_CH;   // 100000
    const int neIn  = in_sizes[11];            // 1000000
    const int neOut = in_sizes[13];

    const int* srcIn  = eiIn;                  // edge_index[0]
    const int* tgtIn  = eiIn + neIn;           // edge_index[1] (sorted)
    const int* srcOut = eiOut;
    const int* tgtOut = eiOut + neOut;

    // Workspace layout: Abf (bf16) | Bbf (bf16) | rpIn | rpOut | WcT (bf16)
    char* ws = (char*)d_ws;
    size_t NH = (size_t)n_nodes * OUT_CH * sizeof(unsigned short);
    unsigned short* Abf = (unsigned short*)ws;
    unsigned short* Bbf = (unsigned short*)(ws + NH);
    int* rpIn  = (int*)(ws + 2 * NH);
    int* rpOut = rpIn + (n_nodes + 1);
    unsigned short* WcT = (unsigned short*)(rpOut + (n_nodes + 1));

    // 1) rowptrs + combined-weight bf16 pre-pack
    int prep_threads = 2 * (n_nodes + 1) + 2 * OUT_CH * IN_CH;
    prep_kernel<<<(prep_threads + 255) / 256, 256, 0, stream>>>(
        tgtIn, tgtOut, Wmi, Wmo, Wsh, rpIn, rpOut, WcT, n_nodes, neIn, neOut);

    // 2) fused dense transform via MFMA (N=128 GEMM: [A|B] columns)
    int gblocks = (n_nodes + M_TILE - 1) / M_TILE;
    gemm_kernel<<<gblocks, 256, 0, stream>>>(x, WcT, Abf, Bbf, n_nodes);

    // 3) segmented gather-sum + epilogue
    prop_kernel<<<(n_nodes + 3) / 4, 256, 0, stream>>>(
        Abf, Bbf, rpIn, rpOut, srcIn, ewIn, srcOut, ewOut,
        bmi, bmo, bsi, bso, Cin, Cout, (float*)d_out, n_nodes);
}